// Round 3
// baseline (138.799 us; speedup 1.0000x reference)
//
#include <hip/hip_runtime.h>

// BottleneckAdapter: out = residual + Wup·( swish(Wl1·n+bl1) * (Wl2·n+bl2) ),
// n = LN( (Wdown·Wproj)·x ).  W_comb = Wdown@Wproj precomputed per-launch.
//
// Dims: B=16 S=2048 C=768 Q=1024 D=64 -> ROWS=32768.
// R3: split main kernel: K_A = x->activated a[] (bottleneck chain),
//     K_B = streaming up-proj + residual (float4 res/out via swapped MFMA operands).

#define ROWS 32768
#define CDIM 768
#define QDIM 1024
#define DDIM 64

typedef __attribute__((ext_vector_type(8))) short bf16x8;
typedef __attribute__((ext_vector_type(4))) float f32x4;

__device__ __forceinline__ ushort f2bf(float f) {
  union { float f; unsigned u; } v; v.f = f;
  unsigned r = v.u + 0x7fffu + ((v.u >> 16) & 1u);   // RNE
  return (ushort)(r >> 16);
}

// ---- K1: partial W_comb[d][c] = sum_q Wdown[d][q]*Wproj[q][c], split in 8 q-chunks.
// part[qc][c][d]  (8 x 768 x 64 f32)
__global__ void k_wcomb(const float* __restrict__ Wproj, const float* __restrict__ Wdown,
                        float* __restrict__ part) {
  int bid = blockIdx.x;                 // 768 blocks = 12 cb * 8 db * 8 qc
  int cb = bid % 12, db = (bid / 12) % 8, qc = bid / 96;
  int l = threadIdx.x;                  // 64
  int c = cb * 64 + l;
  float acc[8];
  #pragma unroll
  for (int i = 0; i < 8; ++i) acc[i] = 0.f;
  int q0 = qc * 128;
  for (int q = q0; q < q0 + 128; ++q) {
    float xp = Wproj[q * CDIM + c];     // coalesced across lanes
    #pragma unroll
    for (int i = 0; i < 8; ++i)
      acc[i] = fmaf(Wdown[(db * 8 + i) * QDIM + q], xp, acc[i]);  // uniform, L2
  }
  #pragma unroll
  for (int i = 0; i < 8; ++i)
    part[((size_t)qc * CDIM + c) * 64 + db * 8 + i] = acc[i];
}

// ---- K2: sum partials + arrange all weights into MFMA fragment order (bf16).
// Fragment convention (k-permutation trick; cancels between the two operands):
// element (lane l, j) of tile (ks,nf) = M[16*nf+(l&15)][32*ks + 8*(l>>4)+j]
__global__ void k_arrange(const float* __restrict__ part, const float* __restrict__ Wup,
                          const float* __restrict__ Wl1, const float* __restrict__ Wl2,
                          ushort* __restrict__ wcf, ushort* __restrict__ wupf,
                          ushort* __restrict__ wl1f, ushort* __restrict__ wl2f) {
  int idx = blockIdx.x * 256 + threadIdx.x;      // 480*256 = 122880 exactly
  if (idx < 49152) {                             // wcf: flat = ((ks*4+nf)*64+l)*8+j, ks<24
    int i0 = idx;
    int j = i0 & 7, l = (i0 >> 3) & 63, t = i0 >> 9;
    int g = l >> 4, r16 = l & 15;
    int nf = t & 3, ks = t >> 2;
    int k = 32 * ks + 8 * g + j, n = 16 * nf + r16;   // k=c-index, n=d-index
    float s = 0.f;
    #pragma unroll
    for (int qc = 0; qc < 8; ++qc) s += part[((size_t)qc * CDIM + k) * 64 + n];
    wcf[i0] = f2bf(s);
  } else if (idx < 49152 + 65536) {              // wupf: flat = ((nf*2+ks)*64+l)*8+j, nf<64
    int i2 = idx - 49152;
    int j = i2 & 7, l = (i2 >> 3) & 63, t = i2 >> 9;
    int g = l >> 4, r16 = l & 15;
    int ks = t & 1, nf = t >> 1;
    int k = 32 * ks + 8 * g + j, n = 16 * nf + r16;   // Wup row n, k-col
    wupf[i2] = f2bf(Wup[n * 64 + k]);
  } else if (idx < 49152 + 65536 + 4096) {       // wl1f: flat = ((ks*4+nf)*64+l)*8+j
    int i3 = idx - (49152 + 65536);
    int j = i3 & 7, l = (i3 >> 3) & 63, t = i3 >> 9;
    int g = l >> 4, r16 = l & 15;
    int nf = t & 3, ks = t >> 2;
    int k = 32 * ks + 8 * g + j, e = 16 * nf + r16;   // o1[e] = sum_k n[k]*Wl1[e][k]
    wl1f[i3] = f2bf(Wl1[e * 64 + k]);
  } else {                                       // wl2f
    int i4 = idx - (49152 + 65536 + 4096);
    int j = i4 & 7, l = (i4 >> 3) & 63, t = i4 >> 9;
    int g = l >> 4, r16 = l & 15;
    int nf = t & 3, ks = t >> 2;
    int k = 32 * ks + 8 * g + j, e = 16 * nf + r16;
    wl2f[i4] = f2bf(Wl2[e * 64 + k]);
  }
}

// ---- K_A: x -> down-proj -> LN -> SwiGLU -> a[] (bf16). 16 rows/WG, 4 waves.
__global__ __launch_bounds__(256, 6)
void k_act(const float* __restrict__ xg,
           const float* __restrict__ gamma, const float* __restrict__ beta,
           const float* __restrict__ bl1, const float* __restrict__ bl2,
           const ushort* __restrict__ wcf,
           const ushort* __restrict__ wl1f, const ushort* __restrict__ wl2f,
           ushort* __restrict__ ag) {
  // Union region, 24832 B:
  //   phase A/B : x_lds [16][776] ushort (full region)
  //   phase B->C: d_lds [16][68]  float  (offset 0; x dead after extra barrier)
  //   phase C->D: n_lds [16][72]  ushort (offset 4608)
  __shared__ ushort smem[12416];
  ushort (*x_lds)[776] = reinterpret_cast<ushort(*)[776]>(smem);
  float  (*d_lds)[68]  = reinterpret_cast<float (*)[68]>(smem);
  ushort (*n_lds)[72]  = reinterpret_cast<ushort(*)[72]>(reinterpret_cast<char*>(smem) + 4608);

  const int tid = threadIdx.x;
  const int w = tid >> 6, l = tid & 63, g = l >> 4, r16 = l & 15;
  const int row0 = blockIdx.x * 16;

  // Phase A: stage x (16x768 f32) -> LDS bf16, float4-vectorized, coalesced.
  #pragma unroll
  for (int i = 0; i < 12; ++i) {
    int f4 = i * 256 + tid;                    // 0..3071
    int r = f4 / 192;                          // 768/4=192 float4 per row
    int c4 = (f4 - r * 192) * 4;
    const float4 v = *reinterpret_cast<const float4*>(xg + (size_t)(row0 + r) * CDIM + c4);
    ushort4 b;
    b.x = f2bf(v.x); b.y = f2bf(v.y); b.z = f2bf(v.z); b.w = f2bf(v.w);
    *reinterpret_cast<ushort4*>(&x_lds[r][c4]) = b;
  }
  __syncthreads();

  // Phase B: d(16x64) = x(16x768) * Wcomb^T. Wave w owns n-frag w.
  f32x4 dacc = {0.f, 0.f, 0.f, 0.f};
  #pragma unroll 8
  for (int ks = 0; ks < 24; ++ks) {
    bf16x8 a = *reinterpret_cast<const bf16x8*>(&x_lds[r16][ks * 32 + 8 * g]);
    bf16x8 b = *reinterpret_cast<const bf16x8*>(wcf + ((size_t)(ks * 4 + w) * 64 + l) * 8);
    dacc = __builtin_amdgcn_mfma_f32_16x16x32_bf16(a, b, dacc, 0, 0, 0);
  }
  __syncthreads();                             // all x reads done before d overwrite
  #pragma unroll
  for (int rg = 0; rg < 4; ++rg) d_lds[4 * g + rg][16 * w + r16] = dacc[rg];
  __syncthreads();

  // Phase C: LayerNorm over D=64. Wave w rows 4w..4w+3; 16 lanes x 4 cols per row.
  {
    int row = 4 * w + g;
    f32x4 v = *reinterpret_cast<const f32x4*>(&d_lds[row][4 * r16]);
    float s  = v[0] + v[1] + v[2] + v[3];
    float sq = v[0]*v[0] + v[1]*v[1] + v[2]*v[2] + v[3]*v[3];
    #pragma unroll
    for (int m = 1; m < 16; m <<= 1) {
      s  += __shfl_xor(s, m, 64);
      sq += __shfl_xor(sq, m, 64);
    }
    float mu  = s * (1.f / 64.f);
    float var = sq * (1.f / 64.f) - mu * mu;
    float rs  = rsqrtf(var + 1e-5f);
    const float4 gm = *reinterpret_cast<const float4*>(gamma + 4 * r16);
    const float4 bt = *reinterpret_cast<const float4*>(beta  + 4 * r16);
    ushort4 nb;
    nb.x = f2bf((v[0] - mu) * rs * gm.x + bt.x);
    nb.y = f2bf((v[1] - mu) * rs * gm.y + bt.y);
    nb.z = f2bf((v[2] - mu) * rs * gm.z + bt.z);
    nb.w = f2bf((v[3] - mu) * rs * gm.w + bt.w);
    *reinterpret_cast<ushort4*>(&n_lds[row][4 * r16]) = nb;
  }
  __syncthreads();

  // Phase D: o1/o2 (16x64, K=64) + bias + swish*gate -> global a[] (bf16).
  {
    bf16x8 a0 = *reinterpret_cast<const bf16x8*>(&n_lds[r16][8 * g]);
    bf16x8 a1 = *reinterpret_cast<const bf16x8*>(&n_lds[r16][32 + 8 * g]);
    bf16x8 b10 = *reinterpret_cast<const bf16x8*>(wl1f + ((size_t)(0 * 4 + w) * 64 + l) * 8);
    bf16x8 b11 = *reinterpret_cast<const bf16x8*>(wl1f + ((size_t)(1 * 4 + w) * 64 + l) * 8);
    bf16x8 b20 = *reinterpret_cast<const bf16x8*>(wl2f + ((size_t)(0 * 4 + w) * 64 + l) * 8);
    bf16x8 b21 = *reinterpret_cast<const bf16x8*>(wl2f + ((size_t)(1 * 4 + w) * 64 + l) * 8);
    f32x4 z = {0.f, 0.f, 0.f, 0.f};
    f32x4 acc1 = __builtin_amdgcn_mfma_f32_16x16x32_bf16(a0, b10, z, 0, 0, 0);
    acc1 = __builtin_amdgcn_mfma_f32_16x16x32_bf16(a1, b11, acc1, 0, 0, 0);
    f32x4 acc2 = __builtin_amdgcn_mfma_f32_16x16x32_bf16(a0, b20, z, 0, 0, 0);
    acc2 = __builtin_amdgcn_mfma_f32_16x16x32_bf16(a1, b21, acc2, 0, 0, 0);
    float bv1 = bl1[16 * w + r16];
    float bv2 = bl2[16 * w + r16];
    #pragma unroll
    for (int rg = 0; rg < 4; ++rg) {
      float o1 = acc1[rg] + bv1;
      float o2 = acc2[rg] + bv2;
      float sw = o1 / (1.f + __expf(-o1));       // o1*sigmoid(o1)
      ag[(size_t)(row0 + 4 * g + rg) * 64 + 16 * w + r16] = f2bf(sw * o2);
    }
  }
}

// ---- K_B: out = res + a * Wup^T. Streaming, float4 res/out.
// Swapped operands: mfma(A=WupFrag, B=aFrag) => lane l holds out-row (l&15),
// out-cols {16*nf + 4*(l>>4) + rg} -> f32x4 acc == float4 of consecutive cols.
__global__ __launch_bounds__(256, 4)
void k_up(const ushort* __restrict__ ag, const float* __restrict__ resg,
          const ushort* __restrict__ wupf, float* __restrict__ outg) {
  __shared__ ushort a_lds[16][68];   // pad 64->68 (2-bank row shift, ~4-way max)
  const int tid = threadIdx.x;
  const int w = tid >> 6, l = tid & 63, g = l >> 4, r16 = l & 15;
  const int row0 = blockIdx.x * 16;

  // stage a-tile (16x64 bf16 = 2KB), coalesced ushort4
  {
    int e = tid * 4;                 // 0..1023
    int r = e >> 6, c = e & 63;
    ushort4 v = *reinterpret_cast<const ushort4*>(ag + (size_t)(row0 + r) * 64 + c);
    *reinterpret_cast<ushort4*>(&a_lds[r][c]) = v;
  }
  __syncthreads();

  const bf16x8 af0 = *reinterpret_cast<const bf16x8*>(&a_lds[r16][8 * g]);        // k 0..31
  const bf16x8 af1 = *reinterpret_cast<const bf16x8*>(&a_lds[r16][32 + 8 * g]);   // k 32..63
  const size_t rowbase = (size_t)(row0 + r16) * QDIM;

  #pragma unroll
  for (int cc = 0; cc < 4; ++cc) {
    bf16x8 wf[8];
    float4 rv[4];
    // wupf loads first (older in vmcnt), then res: MFMA waits only on wupf.
    #pragma unroll
    for (int i = 0; i < 4; ++i) {
      int nf = 16 * w + 4 * cc + i;
      wf[2 * i + 0] = *reinterpret_cast<const bf16x8*>(wupf + ((size_t)(nf * 2 + 0) * 64 + l) * 8);
      wf[2 * i + 1] = *reinterpret_cast<const bf16x8*>(wupf + ((size_t)(nf * 2 + 1) * 64 + l) * 8);
    }
    #pragma unroll
    for (int i = 0; i < 4; ++i) {
      int col = 16 * (16 * w + 4 * cc + i) + 4 * g;
      rv[i] = *reinterpret_cast<const float4*>(resg + rowbase + col);
    }
    #pragma unroll
    for (int i = 0; i < 4; ++i) {
      f32x4 t = {0.f, 0.f, 0.f, 0.f};
      t = __builtin_amdgcn_mfma_f32_16x16x32_bf16(wf[2 * i + 0], af0, t, 0, 0, 0);
      t = __builtin_amdgcn_mfma_f32_16x16x32_bf16(wf[2 * i + 1], af1, t, 0, 0, 0);
      int col = 16 * (16 * w + 4 * cc + i) + 4 * g;
      float4 o;
      o.x = rv[i].x + t[0]; o.y = rv[i].y + t[1];
      o.z = rv[i].z + t[2]; o.w = rv[i].w + t[3];
      *reinterpret_cast<float4*>(outg + rowbase + col) = o;
    }
  }
}

extern "C" void kernel_launch(void* const* d_in, const int* in_sizes, int n_in,
                              void* d_out, int out_size, void* d_ws, size_t ws_size,
                              hipStream_t stream) {
  (void)in_sizes; (void)n_in; (void)out_size; (void)ws_size;
  const float* x     = (const float*)d_in[0];
  const float* resid = (const float*)d_in[1];
  const float* Wproj = (const float*)d_in[2];
  const float* Wdown = (const float*)d_in[3];
  const float* gamma = (const float*)d_in[4];
  const float* beta  = (const float*)d_in[5];
  const float* Wl1   = (const float*)d_in[6];
  const float* bl1   = (const float*)d_in[7];
  const float* Wl2   = (const float*)d_in[8];
  const float* bl2   = (const float*)d_in[9];
  const float* Wup   = (const float*)d_in[10];
  float* out = (float*)d_out;

  char* ws = (char*)d_ws;
  float*  part = (float*)(ws);                   // 8*768*64*4 = 1,572,864 B
  ushort* wcf  = (ushort*)(ws + 1572864);        // 49152*2 =  98,304 B
  ushort* wupf = (ushort*)(ws + 1671168);        // 65536*2 = 131,072 B
  ushort* wl1f = (ushort*)(ws + 1802240);        //  4096*2 =   8,192 B
  ushort* wl2f = (ushort*)(ws + 1810432);        //  4096*2 =   8,192 B
  ushort* ag   = (ushort*)(ws + 1818624);        // 32768*64*2 = 4,194,304 B (end ~6.0MB)

  k_wcomb  <<<768, 64, 0, stream>>>(Wproj, Wdown, part);
  k_arrange<<<480, 256, 0, stream>>>(part, Wup, Wl1, Wl2, wcf, wupf, wl1f, wl2f);
  k_act    <<<2048, 256, 0, stream>>>(x, gamma, beta, bl1, bl2, wcf, wl1f, wl2f, ag);
  k_up     <<<2048, 256, 0, stream>>>(ag, resid, wupf, out);
}

// Round 4
// 103.692 us; speedup vs baseline: 1.3386x; 1.3386x over previous
//
#include <hip/hip_runtime.h>

// BottleneckAdapter: out = residual + Wup·( swish(Wl1·n+bl1) * (Wl2·n+bl2) ),
// n = LN( (Wdown·Wproj)·x ).  W_comb = Wdown@Wproj precomputed per-launch.
//
// Dims: B=16 S=2048 C=768 Q=1024 D=64 -> ROWS=32768.
// R4: k_up rebuilt around global_load_lds DMA for the res stream:
//     - all wupf loads + MFMA first (acc in VGPRs), then 16x 1KB res DMAs
//       per wave into a wave-private LDS slice (128KB in flight per CU),
//       one vmcnt(0), swizzled LDS read, add, nontemporal store.
//     - barrier-free; LDS exactly 64KB; source-side rotation swizzle keeps
//       ds_read_b128 at the inherent 8-round minimum.

#define CDIM 768
#define QDIM 1024

typedef __attribute__((ext_vector_type(8))) short bf16x8;
typedef __attribute__((ext_vector_type(4))) float f32x4;

__device__ __forceinline__ ushort f2bf(float f) {
  union { float f; unsigned u; } v; v.f = f;
  unsigned r = v.u + 0x7fffu + ((v.u >> 16) & 1u);   // RNE
  return (ushort)(r >> 16);
}

__device__ __forceinline__ void gload16(const float* g, float* lds) {
  __builtin_amdgcn_global_load_lds(
      (const __attribute__((address_space(1))) void*)g,
      (__attribute__((address_space(3))) void*)lds, 16, 0, 0);
}

// ---- K1: partial W_comb[d][c] = sum_q Wdown[d][q]*Wproj[q][c], split in 8 q-chunks.
// part[qc][c][d]  (8 x 768 x 64 f32)
__global__ void k_wcomb(const float* __restrict__ Wproj, const float* __restrict__ Wdown,
                        float* __restrict__ part) {
  int bid = blockIdx.x;                 // 768 blocks = 12 cb * 8 db * 8 qc
  int cb = bid % 12, db = (bid / 12) % 8, qc = bid / 96;
  int l = threadIdx.x;                  // 64
  int c = cb * 64 + l;
  float acc[8];
  #pragma unroll
  for (int i = 0; i < 8; ++i) acc[i] = 0.f;
  int q0 = qc * 128;
  for (int q = q0; q < q0 + 128; ++q) {
    float xp = Wproj[q * CDIM + c];     // coalesced across lanes
    #pragma unroll
    for (int i = 0; i < 8; ++i)
      acc[i] = fmaf(Wdown[(db * 8 + i) * QDIM + q], xp, acc[i]);  // uniform, L2
  }
  #pragma unroll
  for (int i = 0; i < 8; ++i)
    part[((size_t)qc * CDIM + c) * 64 + db * 8 + i] = acc[i];
}

// ---- K2: sum partials + arrange all weights into MFMA fragment order (bf16).
// Fragment convention (k-permutation trick; cancels between the two operands):
// element (lane l, j) of tile (ks,nf) = M[16*nf+(l&15)][32*ks + 8*(l>>4)+j]
__global__ void k_arrange(const float* __restrict__ part, const float* __restrict__ Wup,
                          const float* __restrict__ Wl1, const float* __restrict__ Wl2,
                          ushort* __restrict__ wcf, ushort* __restrict__ wupf,
                          ushort* __restrict__ wl1f, ushort* __restrict__ wl2f) {
  int idx = blockIdx.x * 256 + threadIdx.x;      // 480*256 = 122880 exactly
  if (idx < 49152) {                             // wcf: flat = ((ks*4+nf)*64+l)*8+j, ks<24
    int i0 = idx;
    int j = i0 & 7, l = (i0 >> 3) & 63, t = i0 >> 9;
    int g = l >> 4, r16 = l & 15;
    int nf = t & 3, ks = t >> 2;
    int k = 32 * ks + 8 * g + j, n = 16 * nf + r16;   // k=c-index, n=d-index
    float s = 0.f;
    #pragma unroll
    for (int qc = 0; qc < 8; ++qc) s += part[((size_t)qc * CDIM + k) * 64 + n];
    wcf[i0] = f2bf(s);
  } else if (idx < 49152 + 65536) {              // wupf: flat = ((nf*2+ks)*64+l)*8+j, nf<64
    int i2 = idx - 49152;
    int j = i2 & 7, l = (i2 >> 3) & 63, t = i2 >> 9;
    int g = l >> 4, r16 = l & 15;
    int ks = t & 1, nf = t >> 1;
    int k = 32 * ks + 8 * g + j, n = 16 * nf + r16;   // Wup row n, k-col
    wupf[i2] = f2bf(Wup[n * 64 + k]);
  } else if (idx < 49152 + 65536 + 4096) {       // wl1f: flat = ((ks*4+nf)*64+l)*8+j
    int i3 = idx - (49152 + 65536);
    int j = i3 & 7, l = (i3 >> 3) & 63, t = i3 >> 9;
    int g = l >> 4, r16 = l & 15;
    int nf = t & 3, ks = t >> 2;
    int k = 32 * ks + 8 * g + j, e = 16 * nf + r16;   // o1[e] = sum_k n[k]*Wl1[e][k]
    wl1f[i3] = f2bf(Wl1[e * 64 + k]);
  } else {                                       // wl2f
    int i4 = idx - (49152 + 65536 + 4096);
    int j = i4 & 7, l = (i4 >> 3) & 63, t = i4 >> 9;
    int g = l >> 4, r16 = l & 15;
    int nf = t & 3, ks = t >> 2;
    int k = 32 * ks + 8 * g + j, e = 16 * nf + r16;
    wl2f[i4] = f2bf(Wl2[e * 64 + k]);
  }
}

// ---- K_A: x -> down-proj -> LN -> SwiGLU -> a[] (bf16). 16 rows/WG, 4 waves.
__global__ __launch_bounds__(256, 6)
void k_act(const float* __restrict__ xg,
           const float* __restrict__ gamma, const float* __restrict__ beta,
           const float* __restrict__ bl1, const float* __restrict__ bl2,
           const ushort* __restrict__ wcf,
           const ushort* __restrict__ wl1f, const ushort* __restrict__ wl2f,
           ushort* __restrict__ ag) {
  // Union region, 24832 B:
  //   phase A/B : x_lds [16][776] ushort (full region)
  //   phase B->C: d_lds [16][68]  float  (offset 0; x dead after extra barrier)
  //   phase C->D: n_lds [16][72]  ushort (offset 4608)
  __shared__ ushort smem[12416];
  ushort (*x_lds)[776] = reinterpret_cast<ushort(*)[776]>(smem);
  float  (*d_lds)[68]  = reinterpret_cast<float (*)[68]>(smem);
  ushort (*n_lds)[72]  = reinterpret_cast<ushort(*)[72]>(reinterpret_cast<char*>(smem) + 4608);

  const int tid = threadIdx.x;
  const int w = tid >> 6, l = tid & 63, g = l >> 4, r16 = l & 15;
  const int row0 = blockIdx.x * 16;

  // Phase A: stage x (16x768 f32) -> LDS bf16, float4-vectorized, coalesced.
  #pragma unroll
  for (int i = 0; i < 12; ++i) {
    int f4 = i * 256 + tid;                    // 0..3071
    int r = f4 / 192;                          // 768/4=192 float4 per row
    int c4 = (f4 - r * 192) * 4;
    const float4 v = *reinterpret_cast<const float4*>(xg + (size_t)(row0 + r) * CDIM + c4);
    ushort4 b;
    b.x = f2bf(v.x); b.y = f2bf(v.y); b.z = f2bf(v.z); b.w = f2bf(v.w);
    *reinterpret_cast<ushort4*>(&x_lds[r][c4]) = b;
  }
  __syncthreads();

  // Phase B: d(16x64) = x(16x768) * Wcomb^T. Wave w owns n-frag w.
  f32x4 dacc = {0.f, 0.f, 0.f, 0.f};
  #pragma unroll 8
  for (int ks = 0; ks < 24; ++ks) {
    bf16x8 a = *reinterpret_cast<const bf16x8*>(&x_lds[r16][ks * 32 + 8 * g]);
    bf16x8 b = *reinterpret_cast<const bf16x8*>(wcf + ((size_t)(ks * 4 + w) * 64 + l) * 8);
    dacc = __builtin_amdgcn_mfma_f32_16x16x32_bf16(a, b, dacc, 0, 0, 0);
  }
  __syncthreads();                             // all x reads done before d overwrite
  #pragma unroll
  for (int rg = 0; rg < 4; ++rg) d_lds[4 * g + rg][16 * w + r16] = dacc[rg];
  __syncthreads();

  // Phase C: LayerNorm over D=64. Wave w rows 4w..4w+3; 16 lanes x 4 cols per row.
  {
    int row = 4 * w + g;
    f32x4 v = *reinterpret_cast<const f32x4*>(&d_lds[row][4 * r16]);
    float s  = v[0] + v[1] + v[2] + v[3];
    float sq = v[0]*v[0] + v[1]*v[1] + v[2]*v[2] + v[3]*v[3];
    #pragma unroll
    for (int m = 1; m < 16; m <<= 1) {
      s  += __shfl_xor(s, m, 64);
      sq += __shfl_xor(sq, m, 64);
    }
    float mu  = s * (1.f / 64.f);
    float var = sq * (1.f / 64.f) - mu * mu;
    float rs  = rsqrtf(var + 1e-5f);
    const float4 gm = *reinterpret_cast<const float4*>(gamma + 4 * r16);
    const float4 bt = *reinterpret_cast<const float4*>(beta  + 4 * r16);
    ushort4 nb;
    nb.x = f2bf((v[0] - mu) * rs * gm.x + bt.x);
    nb.y = f2bf((v[1] - mu) * rs * gm.y + bt.y);
    nb.z = f2bf((v[2] - mu) * rs * gm.z + bt.z);
    nb.w = f2bf((v[3] - mu) * rs * gm.w + bt.w);
    *reinterpret_cast<ushort4*>(&n_lds[row][4 * r16]) = nb;
  }
  __syncthreads();

  // Phase D: o1/o2 (16x64, K=64) + bias + swish*gate -> global a[] (bf16).
  {
    bf16x8 a0 = *reinterpret_cast<const bf16x8*>(&n_lds[r16][8 * g]);
    bf16x8 a1 = *reinterpret_cast<const bf16x8*>(&n_lds[r16][32 + 8 * g]);
    bf16x8 b10 = *reinterpret_cast<const bf16x8*>(wl1f + ((size_t)(0 * 4 + w) * 64 + l) * 8);
    bf16x8 b11 = *reinterpret_cast<const bf16x8*>(wl1f + ((size_t)(1 * 4 + w) * 64 + l) * 8);
    bf16x8 b20 = *reinterpret_cast<const bf16x8*>(wl2f + ((size_t)(0 * 4 + w) * 64 + l) * 8);
    bf16x8 b21 = *reinterpret_cast<const bf16x8*>(wl2f + ((size_t)(1 * 4 + w) * 64 + l) * 8);
    f32x4 z = {0.f, 0.f, 0.f, 0.f};
    f32x4 acc1 = __builtin_amdgcn_mfma_f32_16x16x32_bf16(a0, b10, z, 0, 0, 0);
    acc1 = __builtin_amdgcn_mfma_f32_16x16x32_bf16(a1, b11, acc1, 0, 0, 0);
    f32x4 acc2 = __builtin_amdgcn_mfma_f32_16x16x32_bf16(a0, b20, z, 0, 0, 0);
    acc2 = __builtin_amdgcn_mfma_f32_16x16x32_bf16(a1, b21, acc2, 0, 0, 0);
    float bv1 = bl1[16 * w + r16];
    float bv2 = bl2[16 * w + r16];
    #pragma unroll
    for (int rg = 0; rg < 4; ++rg) {
      float o1 = acc1[rg] + bv1;
      float o2 = acc2[rg] + bv2;
      float sw = o1 / (1.f + __expf(-o1));       // o1*sigmoid(o1)
      ag[(size_t)(row0 + 4 * g + rg) * 64 + 16 * w + r16] = f2bf(sw * o2);
    }
  }
}

// ---- K_B: out = res + a * Wup^T.  DMA-pipelined streaming kernel.
// Lane l (wave w): out-row = l&15, out-cols 16*(16w+nfl)+4*(l>>4)+{0..3}.
// res staged via global_load_lds into wave-private [16][256] f32 slice
// (cols 256w..256w+255), with per-row lane rotation (source-side swizzle)
// so the column-slice reads spread across banks.
__global__ __launch_bounds__(256, 2)
void k_up(const ushort* __restrict__ ag, const float* __restrict__ resg,
          const ushort* __restrict__ wupf, float* __restrict__ outg) {
  __shared__ float res_lds[4][16][256];   // exactly 64 KiB, wave-private slices
  const int tid = threadIdx.x;
  const int w = tid >> 6, l = tid & 63, g = l >> 4, r16 = l & 15;
  const int row0 = blockIdx.x * 16;

  // a-fragments straight from global (2KB tile, permuted but segment-coalesced)
  const bf16x8 af0 = *reinterpret_cast<const bf16x8*>(ag + (size_t)(row0 + r16) * 64 + 8 * g);
  const bf16x8 af1 = *reinterpret_cast<const bf16x8*>(ag + (size_t)(row0 + r16) * 64 + 32 + 8 * g);

  // Product first: acc[nfl] = up-proj fragment (out-cols 16*(16w+nfl)+4g+rg).
  // All wupf loads are older than the DMAs below, so their vmcnt waits
  // don't touch the res stream.
  f32x4 acc[16];
  #pragma unroll
  for (int nfl = 0; nfl < 16; ++nfl) {
    int nf = 16 * w + nfl;
    bf16x8 b0 = *reinterpret_cast<const bf16x8*>(wupf + ((size_t)(nf * 2 + 0) * 64 + l) * 8);
    bf16x8 b1 = *reinterpret_cast<const bf16x8*>(wupf + ((size_t)(nf * 2 + 1) * 64 + l) * 8);
    f32x4 t = {0.f, 0.f, 0.f, 0.f};
    t = __builtin_amdgcn_mfma_f32_16x16x32_bf16(b0, af0, t, 0, 0, 0);
    acc[nfl] = __builtin_amdgcn_mfma_f32_16x16x32_bf16(b1, af1, t, 0, 0, 0);
  }
  __builtin_amdgcn_sched_barrier(0);   // keep DMAs after all wupf/MFMA

  // res DMA: 16 rows x 1KB into this wave's slice. Row i rotated by i quads
  // on the SOURCE side (dest stays linear as global_load_lds requires).
  #pragma unroll
  for (int i = 0; i < 16; ++i) {
    const float* gsrc = resg + (size_t)(row0 + i) * QDIM + 256 * w + 4 * ((l + i) & 63);
    gload16(gsrc, &res_lds[w][i][0]);
  }
  asm volatile("s_waitcnt vmcnt(0)" ::: "memory");
  __builtin_amdgcn_sched_barrier(0);
  // no __syncthreads: each wave reads only its own slice

  // add + nontemporal store (keep out from evicting x/res in L3)
  #pragma unroll
  for (int nfl = 0; nfl < 16; ++nfl) {
    int qr = (4 * nfl + g - r16) & 63;         // undo source rotation of row r16
    const f32x4 rv = *reinterpret_cast<const f32x4*>(&res_lds[w][r16][4 * qr]);
    f32x4 o = rv + acc[nfl];
    f32x4* dst = reinterpret_cast<f32x4*>(
        outg + (size_t)(row0 + r16) * QDIM + 16 * (16 * w + nfl) + 4 * g);
    __builtin_nontemporal_store(o, dst);
  }
}

extern "C" void kernel_launch(void* const* d_in, const int* in_sizes, int n_in,
                              void* d_out, int out_size, void* d_ws, size_t ws_size,
                              hipStream_t stream) {
  (void)in_sizes; (void)n_in; (void)out_size; (void)ws_size;
  const float* x     = (const float*)d_in[0];
  const float* resid = (const float*)d_in[1];
  const float* Wproj = (const float*)d_in[2];
  const float* Wdown = (const float*)d_in[3];
  const float* gamma = (const float*)d_in[4];
  const float* beta  = (const float*)d_in[5];
  const float* Wl1   = (const float*)d_in[6];
  const float* bl1   = (const float*)d_in[7];
  const float* Wl2   = (const float*)d_in[8];
  const float* bl2   = (const float*)d_in[9];
  const float* Wup   = (const float*)d_in[10];
  float* out = (float*)d_out;

  char* ws = (char*)d_ws;
  float*  part = (float*)(ws);                   // 8*768*64*4 = 1,572,864 B
  ushort* wcf  = (ushort*)(ws + 1572864);        // 49152*2 =  98,304 B
  ushort* wupf = (ushort*)(ws + 1671168);        // 65536*2 = 131,072 B
  ushort* wl1f = (ushort*)(ws + 1802240);        //  4096*2 =   8,192 B
  ushort* wl2f = (ushort*)(ws + 1810432);        //  4096*2 =   8,192 B
  ushort* ag   = (ushort*)(ws + 1818624);        // 32768*64*2 = 4,194,304 B (end ~6.0MB)

  k_wcomb  <<<768, 64, 0, stream>>>(Wproj, Wdown, part);
  k_arrange<<<480, 256, 0, stream>>>(part, Wup, Wl1, Wl2, wcf, wupf, wl1f, wl2f);
  k_act    <<<2048, 256, 0, stream>>>(x, gamma, beta, bl1, bl2, wcf, wl1f, wl2f, ag);
  k_up     <<<2048, 256, 0, stream>>>(ag, resid, wupf, out);
}